// Round 4
// baseline (226.740 us; speedup 1.0000x reference)
//
#include <hip/hip_runtime.h>
#include <hip/hip_bf16.h>
#include <math.h>

// TreeLSTM, B=8, L=4096, D=300, H=128, 12 levels. Round 10:
// - Levels 1..8 now run as FOUR fused two-level kernels ({1,2},{3,4},{5,6},
//   {7,8}). Tree locality: L+1 row m needs only L rows 2m,2m+1, so a block
//   computing 128 level-L rows (all 128 h cols, 8 waves = 8 h-groups) can
//   finish 64 level-(L+1) rows from its own LDS. Odd-level h/c never touch
//   HBM (saves ~33 MB w+r) and launches drop 11 -> 7.
// - h_L kept as bf16 LDS image with XOR swizzle ((row>>1)&7)<<4 (read as
//   16B A-fragments, 2-way conflict); c_L fp32 LDS. Level L writes, barrier,
//   level L+1 reads -- no R8-class intra-level RAW hazard.
// - leaf (fused x fp32->bf16 convert), finish (levels 9..12, single block),
//   reorder unchanged from R9 (known good).

typedef __attribute__((ext_vector_type(8))) short bfrag8;   // 8 bf16 = 4 VGPRs
typedef __attribute__((ext_vector_type(4))) float f32x4;

__device__ __forceinline__ float rcpf(float x) { return __builtin_amdgcn_rcpf(x); }
__device__ __forceinline__ float sigf(float x) { return rcpf(1.0f + __expf(-x)); }
__device__ __forceinline__ float tanh_f(float x) {
    float e = __expf(2.0f * x);              // x>>0: e=inf -> rcp=0 -> 1 ; x<<0: e=0 -> -1
    return 1.0f - 2.0f * rcpf(e + 1.0f);
}
__device__ __forceinline__ short f2bf(float f) {
    __hip_bfloat16 h = __float2bfloat16(f);
    return *reinterpret_cast<short*>(&h);
}
__device__ __forceinline__ bfrag8 pack8(f32x4 a, f32x4 b) {
    union { int i[4]; bfrag8 v; } u;
    asm("v_cvt_pk_bf16_f32 %0, %1, %2" : "=v"(u.i[0]) : "v"(a[0]), "v"(a[1]));
    asm("v_cvt_pk_bf16_f32 %0, %1, %2" : "=v"(u.i[1]) : "v"(a[2]), "v"(a[3]));
    asm("v_cvt_pk_bf16_f32 %0, %1, %2" : "=v"(u.i[2]) : "v"(b[0]), "v"(b[1]));
    asm("v_cvt_pk_bf16_f32 %0, %1, %2" : "=v"(u.i[3]) : "v"(b[2]), "v"(b[3]));
    return u.v;
}
#define GLDS(gp, lp) __builtin_amdgcn_global_load_lds( \
    (const __attribute__((address_space(1))) void*)(gp), \
    (__attribute__((address_space(3))) void*)(lp), 16, 0, 0)

// ---------------- weight reorder (once, tiny) ----------------
// Wcat_ch : chunk layout [c:0..31][n:0..640) ; n = g*128+h ; k<128 -> W_l, else W_r.
// Wleaf_ch: chunk layout [c:0..39][n:0..256) ; k<300 valid else 0.
__global__ __launch_bounds__(256) void reorder_kernel(
    const float* __restrict__ W_l, const float* __restrict__ W_r,
    const float* __restrict__ W_leaf,
    short* __restrict__ Wcat_ch, short* __restrict__ Wleaf_ch)
{
    int idx = blockIdx.x * 256 + threadIdx.x;
    if (idx < 163840) {
        int n = idx >> 8, k = idx & 255;
        float v = (k < 128) ? W_l[k * 640 + n] : W_r[(k - 128) * 640 + n];
        Wcat_ch[(((size_t)(k >> 3)) * 640 + n) * 8 + (k & 7)] = f2bf(v);
        return;
    }
    idx -= 163840;
    if (idx < 81920) {
        int n = idx / 320, k = idx - n * 320;
        short v = (k < 300) ? f2bf(W_leaf[k * 256 + n]) : (short)0;
        Wleaf_ch[(((size_t)(k >> 3)) * 256 + n) * 8 + (k & 7)] = v;
    }
}

// ---------------- leaf (fused x-convert): [32768,320fp32]@[320,256bf16] ----------------
__global__ __launch_bounds__(256) void leaf_kernel(
    const float* __restrict__ x, const short* __restrict__ Bw,
    const float* __restrict__ bleaf,
    short* __restrict__ hD,       // level-1 A, chunk layout [32][16384] units
    float* __restrict__ cD)       // [32768][128] fp32
{
    __shared__ float Als[128 * 64];     // 32 KB: [row][16 units of 4 floats], swizzled
    __shared__ short Bls[8 * 128 * 8];  // 16 KB: [c][n] units
    const int tid  = threadIdx.x;
    const int w    = tid >> 6, lane = tid & 63;
    const int quad = lane >> 4, l16 = lane & 15;
    const int mBlk = blockIdx.x * 128, nBlk = blockIdx.y * 128;
    const int waveM = (w >> 1) * 64, waveN = (w & 1) * 64;

    f32x4 acc[4][4] = {};
    const f32x4 zero4 = {0.f, 0.f, 0.f, 0.f};

    for (int c = 0; c < 5; ++c) {           // K = 5 * 64 = 320 (300 + zero pad)
        const int k0 = c * 64;
        {
            const int q_lds = lane & 15;
            const int rsub  = lane >> 4;
            #pragma unroll
            for (int g = 0; g < 8; ++g) {
                int row = w * 32 + g * 4 + rsub;
                int q_g = (q_lds & 8) | ((q_lds & 7) ^ (row & 7));
                if (c < 4 || q_g < 11) {
                    GLDS(x + (size_t)(mBlk + row) * 300 + k0 + q_g * 4,
                         (char*)Als + (w * 32 + g * 4) * 256);
                } else {
                    *(f32x4*)((char*)Als + row * 256 + q_lds * 16) = zero4;  // pad k=300..319
                }
            }
        }
        #pragma unroll
        for (int g2 = 0; g2 < 4; ++g2) {
            int u = w * 4 + g2;   // 0..15 -> cc = u>>1, half = u&1
            GLDS(Bw + ((size_t)(c * 8 + (u >> 1)) * 256 + nBlk + (u & 1) * 64 + lane) * 8,
                 (char*)Bls + u * 1024);
        }
        __syncthreads();
        #pragma unroll
        for (int ks = 0; ks < 2; ++ks) {
            const int ca = ks * 4 + quad;
            bfrag8 af[4], bf4[4];
            #pragma unroll
            for (int i = 0; i < 4; ++i) {
                int r  = waveM + i * 16 + l16;
                int u0 = 2 * ca, u1 = 2 * ca + 1;
                int s0 = (u0 & 8) | ((u0 & 7) ^ (r & 7));
                int s1 = (u1 & 8) | ((u1 & 7) ^ (r & 7));
                f32x4 a0 = *(const f32x4*)(Als + r * 64 + s0 * 4);
                f32x4 a1 = *(const f32x4*)(Als + r * 64 + s1 * 4);
                af[i] = pack8(a0, a1);
            }
            #pragma unroll
            for (int jn = 0; jn < 4; ++jn)
                bf4[jn] = *(const bfrag8*)(Bls + (ca * 128 + waveN + jn * 16 + l16) * 8);
            #pragma unroll
            for (int i = 0; i < 4; ++i)
                #pragma unroll
                for (int jn = 0; jn < 4; ++jn)
                    acc[i][jn] = __builtin_amdgcn_mfma_f32_16x16x32_bf16(
                                     af[i], bf4[jn], acc[i][jn], 0, 0, 0);
        }
        __syncthreads();
    }

    #pragma unroll
    for (int i = 0; i < 4; ++i) {
        int row0 = mBlk + waveM + i * 16 + quad * 4;
        #pragma unroll
        for (int jn = 0; jn < 4; ++jn) {
            int col = nBlk + waveN + jn * 16 + l16;
            float bv = bleaf[col];
            #pragma unroll
            for (int rg = 0; rg < 4; ++rg) {
                float v = acc[i][jn][rg] + bv;
                int m = row0 + rg;
                if (nBlk == 0) {
                    int hc = col;
                    hD[(((size_t)((m & 1) * 16 + (hc >> 3))) * 16384 + (m >> 1)) * 8
                       + (hc & 7)] = f2bf(v);
                } else {
                    cD[(size_t)m * 128 + (col - 128)] = v;
                }
            }
        }
    }
}

// ---------------- fused two-level kernel: levels L, L+1 ----------------
// Block: 512 thr, 8 waves = 8 h-groups (all 128 h cols). Owns 64 L+1-outputs
// = 128 L-outputs. Level L: 2 sub-tiles of 64 rows (A staged 32 KB each),
// epilogue -> hL bf16 LDS image (XOR swizzled) + cL fp32 LDS. Level L+1:
// A-frags from hL, c from cL, outputs -> global. LDS 32+32+64 = 128 KB.
__global__ __launch_bounds__(512, 2) void fused2_kernel(
    const short* __restrict__ A,      // [32][2*M2] chunk units (level-L A)
    const float* __restrict__ cprev,  // [4*M2][128] fp32
    const short* __restrict__ Wch,    // [32][640] chunk units
    const float* __restrict__ bias,   // [640]
    short* __restrict__ hout,         // level-(L+1) h, chunk stride M2>>1
    float* __restrict__ cout_,        // [M2][128] fp32
    int M2)                           // level-(L+1) output rows
{
    __shared__ short Als[32 * 64 * 8];   // 32 KB: staged A sub-tile
    __shared__ short hL [128 * 128];     // 32 KB: level-L h image (swizzled)
    __shared__ float cL [128 * 128];     // 64 KB: level-L c
    const int tid  = threadIdx.x;
    const int w    = tid >> 6, lane = tid & 63;
    const int quad = lane >> 4, l16 = lane & 15;
    const int h    = w * 16 + l16;       // wave = h-group
    const int M1   = M2 * 2;
    const int Lbase = blockIdx.x * 128;  // level-L rows [Lbase, Lbase+128)

    // W fragments (VGPR), shared by both levels
    bfrag8 Wfr[5][8];
    #pragma unroll
    for (int g = 0; g < 5; ++g)
        #pragma unroll
        for (int s = 0; s < 8; ++s)
            Wfr[g][s] = *(const bfrag8*)(Wch + ((size_t)(s * 4 + quad) * 640
                                                + g * 128 + h) * 8);
    const float bi  = bias[h],       bfl = bias[128 + h], bfr_ = bias[256 + h];
    const float bo  = bias[384 + h], bg  = bias[512 + h];

    // ---- level L: two 64-row sub-tiles ----
    for (int st = 0; st < 2; ++st) {
        #pragma unroll
        for (int s = 0; s < 4; ++s)      // 8 waves x 4 GLDS = 32 KB
            GLDS(A + ((size_t)(s * 8 + w) * M1 + Lbase + st * 64 + lane) * 8,
                 (char*)Als + (s * 8 + w) * 1024);
        __syncthreads();

        for (int rt = 0; rt < 4; ++rt) {
            f32x4 acc[5] = {};
            #pragma unroll
            for (int s = 0; s < 8; ++s) {
                bfrag8 af = *(const bfrag8*)(Als + ((s * 4 + quad) * 64
                                                    + rt * 16 + l16) * 8);
                #pragma unroll
                for (int g = 0; g < 5; ++g)
                    acc[g] = __builtin_amdgcn_mfma_f32_16x16x32_bf16(
                                 af, Wfr[g][s], acc[g], 0, 0, 0);
            }
            #pragma unroll
            for (int rg = 0; rg < 4; ++rg) {
                int mloc = rt * 16 + quad * 4 + rg;      // [0,64)
                int mG   = Lbase + st * 64 + mloc;       // global level-L row
                float gi  = acc[0][rg] + bi;
                float gfl = acc[1][rg] + bfl;
                float gfr = acc[2][rg] + bfr_;
                float go  = acc[3][rg] + bo;
                float gg  = acc[4][rg] + bg;
                float cl  = cprev[(size_t)(2 * mG) * 128 + h];
                float cr  = cprev[(size_t)(2 * mG + 1) * 128 + h];
                float cn  = sigf(gfl) * cl + sigf(gfr) * cr + sigf(gi) * tanh_f(gg);
                float hn  = sigf(go) * tanh_f(cn);
                int row = st * 64 + mloc;                // [0,128)
                cL[row * 128 + h] = cn;
                int byte = (row * 256 + h * 2) ^ (((row >> 1) & 7) << 4);
                *(short*)((char*)hL + byte) = f2bf(hn);
            }
        }
        __syncthreads();   // Als reusable; hL/cL (after st=1) complete
    }

    // ---- level L+1: 64 output rows from LDS ----
    const int Mn2 = M2 >> 1;
    for (int rt = 0; rt < 4; ++rt) {
        f32x4 acc[5] = {};
        #pragma unroll
        for (int s = 0; s < 8; ++s) {
            int c    = s * 4 + quad;
            int row  = 2 * (rt * 16 + l16) + (c >> 4);   // child row in hL
            int byte = (row * 256 + (c & 15) * 16) ^ (((row >> 1) & 7) << 4);
            bfrag8 af = *(const bfrag8*)((const char*)hL + byte);
            #pragma unroll
            for (int g = 0; g < 5; ++g)
                acc[g] = __builtin_amdgcn_mfma_f32_16x16x32_bf16(
                             af, Wfr[g][s], acc[g], 0, 0, 0);
        }
        #pragma unroll
        for (int rg = 0; rg < 4; ++rg) {
            int mloc = rt * 16 + quad * 4 + rg;          // [0,64)
            int m2   = blockIdx.x * 64 + mloc;           // global L+1 row
            float gi  = acc[0][rg] + bi;
            float gfl = acc[1][rg] + bfl;
            float gfr = acc[2][rg] + bfr_;
            float go  = acc[3][rg] + bo;
            float gg  = acc[4][rg] + bg;
            float cl  = cL[(2 * mloc) * 128 + h];
            float cr  = cL[(2 * mloc + 1) * 128 + h];
            float cn  = sigf(gfl) * cl + sigf(gfr) * cr + sigf(gi) * tanh_f(gg);
            float hn  = sigf(go) * tanh_f(cn);
            hout[(((size_t)((m2 & 1) * 16 + (h >> 3))) * Mn2 + (m2 >> 1)) * 8
                 + (h & 7)] = f2bf(hn);
            cout_[(size_t)m2 * 128 + h] = cn;
        }
    }
}

// ---------------- single-block finisher: levels 9..12 ----------------
__global__ __launch_bounds__(512) void finish_kernel(
    const short* __restrict__ hin,   // [32][64] units (128-row chunk layout)
    const float* __restrict__ cin,   // [128][128] f32
    const short* __restrict__ Wch, const float* __restrict__ bias,
    float* __restrict__ out)         // [8][128]
{
    __shared__ short hP[32 * 64 * 8];   // 32 KB ping
    __shared__ short hQ[32 * 32 * 8];   // 16 KB pong
    __shared__ float cA[128 * 128];     // 64 KB
    __shared__ float cB[64 * 128];      // 32 KB
    const int tid  = threadIdx.x;
    const int w    = tid >> 6, lane = tid & 63;
    const int quad = lane >> 4, l16 = lane & 15;
    const int h    = w * 16 + l16;      // wave = h-group

    #pragma unroll
    for (int g = 0; g < 4; ++g)
        GLDS(hin + ((size_t)((g * 8 + w) * 64 + lane)) * 8,
             (char*)hP + ((g * 8 + w) * 64) * 16);
    #pragma unroll
    for (int g = 0; g < 8; ++g)
        GLDS(cin + ((size_t)((g * 8 + w) * 64 + lane)) * 4,
             (char*)cA + ((g * 8 + w) * 64) * 16);

    bfrag8 Wfr[5][8];
    #pragma unroll
    for (int g = 0; g < 5; ++g)
        #pragma unroll
        for (int s = 0; s < 8; ++s)
            Wfr[g][s] = *(const bfrag8*)(Wch + ((size_t)(s * 4 + quad) * 640
                                                + g * 128 + h) * 8);
    const float bi  = bias[h],       bfl = bias[128 + h], bfr_ = bias[256 + h];
    const float bo  = bias[384 + h], bg  = bias[512 + h];

    __syncthreads();

    #pragma unroll
    for (int t = 0; t < 4; ++t) {              // levels 9..12
        const int Mo = 64 >> t;                // 64, 32, 16, 8
        const short* hsrc = (t & 1) ? hQ : hP;
        short* hdst       = (t & 1) ? hP : hQ;
        const float* cread  = (t & 1) ? cB : cA;
        float*       cwrite = (t & 1) ? cA : cB;
        const int nrt = (Mo + 15) >> 4;

        for (int rt = 0; rt < nrt; ++rt) {
            f32x4 acc[5] = {};
            #pragma unroll
            for (int s = 0; s < 8; ++s) {
                bfrag8 af = *(const bfrag8*)(hsrc + ((s * 4 + quad) * Mo
                                                     + rt * 16 + l16) * 8);
                #pragma unroll
                for (int g = 0; g < 5; ++g)
                    acc[g] = __builtin_amdgcn_mfma_f32_16x16x32_bf16(
                                 af, Wfr[g][s], acc[g], 0, 0, 0);
            }
            #pragma unroll
            for (int rg = 0; rg < 4; ++rg) {
                int m = rt * 16 + quad * 4 + rg;
                if (m < Mo) {
                    float gi  = acc[0][rg] + bi;
                    float gfl = acc[1][rg] + bfl;
                    float gfr = acc[2][rg] + bfr_;
                    float go  = acc[3][rg] + bo;
                    float gg  = acc[4][rg] + bg;
                    float cl  = cread[(2 * m) * 128 + h];
                    float cr  = cread[(2 * m + 1) * 128 + h];
                    float cn  = sigf(gfl) * cl + sigf(gfr) * cr + sigf(gi) * tanh_f(gg);
                    float hn  = sigf(go) * tanh_f(cn);
                    if (t == 3) {
                        out[(size_t)m * 128 + h] = hn;
                    } else {
                        hdst[(((m & 1) * 16 + (h >> 3)) * (Mo >> 1) + (m >> 1)) * 8
                             + (h & 7)] = f2bf(hn);
                        cwrite[m * 128 + h] = cn;
                    }
                }
            }
        }
        __syncthreads();
    }
}

extern "C" void kernel_launch(void* const* d_in, const int* in_sizes, int n_in,
                              void* d_out, int out_size, void* d_ws, size_t ws_size,
                              hipStream_t stream)
{
    const float* x      = (const float*)d_in[0];
    const float* W_leaf = (const float*)d_in[1];
    const float* b_leaf = (const float*)d_in[2];
    const float* W_l    = (const float*)d_in[3];
    const float* W_r    = (const float*)d_in[4];
    const float* b      = (const float*)d_in[5];
    float* out = (float*)d_out;

    // workspace (~38.5 MB)
    char* p = (char*)d_ws;
    short* hA    = (short*)p; p += (size_t)32 * 16384 * 16 + 1024; //  8.4 MB
    short* hB    = (short*)p; p += (size_t)32 * 8192 * 16 + 1024;  //  4.2 MB
    float* c0    = (float*)p; p += (size_t)32768 * 128 * 4;        // 16.8 MB
    float* c1    = (float*)p; p += (size_t)16384 * 128 * 4;        //  8.4 MB
    short* WcatC = (short*)p; p += (size_t)32 * 640 * 16;          // 320 KB
    short* WlfC  = (short*)p; p += (size_t)40 * 256 * 16;          // 160 KB

    reorder_kernel<<<960, 256, 0, stream>>>(W_l, W_r, W_leaf, WcatC, WlfC);
    leaf_kernel<<<dim3(256, 2), 256, 0, stream>>>(x, WlfC, b_leaf, hA, c0);

    // levels 1..8 as four fused pairs (ping-pong hA/c0 <-> hB/c1)
    fused2_kernel<<<128, 512, 0, stream>>>(hA, c0, WcatC, b, hB, c1, 8192); // L1,2
    fused2_kernel<<< 32, 512, 0, stream>>>(hB, c1, WcatC, b, hA, c0, 2048); // L3,4
    fused2_kernel<<<  8, 512, 0, stream>>>(hA, c0, WcatC, b, hB, c1,  512); // L5,6
    fused2_kernel<<<  2, 512, 0, stream>>>(hB, c1, WcatC, b, hA, c0,  128); // L7,8

    // levels 9..12: single-block finisher (input: hA [32][64], c0 [128][128])
    finish_kernel<<<1, 512, 0, stream>>>(hA, c0, WcatC, b, out);
}